// Round 2
// baseline (12699.859 us; speedup 1.0000x reference)
//
#include <hip/hip_runtime.h>

// ---------------------------------------------------------------------------
// Problem constants
// ---------------------------------------------------------------------------
constexpr int Bq = 4, Sq = 4096, Dq = 1024, Hq = 16, Eq = 8, HIDq = 4096;
constexpr int Tq = Bq * Sq;               // 16384 tokens
constexpr long TD = (long)Tq * Dq;        // 16,777,216

constexpr int PADT = 33792;               // max padded MoE slots (2T + 8*128)
constexpr int CH   = 3840;                // MoE chunk rows (30*128)
constexpr int NC   = 9;                   // ceil(PADT / CH)
constexpr int QCN  = 1024;                // seq chunk for qkv/attn
constexpr int QROWS = 4 * QCN;            // 4096 rows per qkv chunk

// ---------------------------------------------------------------------------
// Workspace layout (float offsets). Peak = 32,768,000 floats = 125 MiB.
//   small ints/floats | xc (phase A) / moe (phase B) | qkv chunk + wt (A) /
//                                                      h chunk (B, same span)
// ---------------------------------------------------------------------------
constexpr long OFF_SM = 0;                          // 262144 floats
constexpr long OFF_XC = 262144;                     // TD
constexpr long OFF_Q  = OFF_XC + TD;                // QROWS*3*D = 12,582,912
constexpr long OFF_WT = OFF_Q + (long)QROWS * 3 * Dq;  // 3*D*D = 3,145,728
// phase B: h chunk @ OFF_Q, CH*HID = 15,728,640 floats (spans Q+WT exactly)

// ---------------------------------------------------------------------------
// GEMM: C[.,N] = op(A) @ B + bias, 128x128 tile, BK=16, 256 thr, 8x8 micro
// AMODE: 0 direct rows          1 conv-gather from x (shifted seq)
//        4 qkv-chunk gather     5 MoE list-gather (padded slots)
//        6 MoE direct h rows (padded slots)
// BTRANS: 0 B is KxN row-major; 1 B is NxK row-major (torch Linear weight)
// EPI: 0 bias store; 1 bias+relu store; 2 bias + C_old accumulate store;
//      3 weighted atomicAdd into moe (exactly 2 adds/elem -> deterministic)
// ---------------------------------------------------------------------------
#define BM 128
#define BN 128
#define BK 16
#define LDP 132

template <int AMODE, int BTRANS, int EPI>
__global__ __launch_bounds__(256) void gemm_k(
    const float* __restrict__ A, const float* __restrict__ Bm,
    const float* __restrict__ bias, float* __restrict__ C,
    int K, int lda, int ldb, int ldc,
    const int* __restrict__ list, const float* __restrict__ wslot,
    const int* __restrict__ offsp, const int* __restrict__ counts,
    float* __restrict__ moe, int chunk_base, int nbase,
    long bstride, int biasstride) {
  __shared__ float As[BK][LDP];
  __shared__ float Bs[BK][LDP];

  const int t = threadIdx.x;
  int count_e = 0, lr0 = 0, r0 = 0;
  const float* Bp = Bm;
  const float* biasp = bias;
  if (AMODE >= 5) {
    r0 = chunk_base + blockIdx.y * BM;
    if (r0 >= offsp[8]) return;
    int e = 0;
    while (r0 >= offsp[e + 1]) e++;
    count_e = counts[e];
    lr0 = r0 - offsp[e];
    Bp = Bm + (long)e * bstride;
    biasp = bias + (long)e * biasstride;
  }
  const int m0 = blockIdx.y * BM;
  const int n0 = blockIdx.x * BN;
  const int tx = t & 15, ty = t >> 4;

  // per-slot A row pointers (constant across K loop)
  const float* arp[2];
  int abat[2], asrow[2];
  bool aval[2];
  #pragma unroll
  for (int i = 0; i < 2; i++) {
    const int f = t + 256 * i;
    const int m = f >> 2;
    aval[i] = true;
    if (AMODE == 0) {
      arp[i] = A + (long)(m0 + m) * lda;
    } else if (AMODE == 1) {
      abat[i] = (m0 + m) >> 12;
      asrow[i] = (m0 + m) & 4095;
      arp[i] = A;
    } else if (AMODE == 4) {
      const int mm = m0 + m;
      const int l = mm >> 10;
      const int n = nbase + (mm & 1023);
      arp[i] = A + (long)(l * Sq + n) * lda;
    } else if (AMODE == 5) {
      const int lr = lr0 + m;
      aval[i] = (lr < count_e);
      const int tok = aval[i] ? list[r0 + m] : 0;
      arp[i] = A + (long)tok * lda;
    } else {  // AMODE == 6
      const int lr = lr0 + m;
      aval[i] = (lr < count_e);
      arp[i] = A + (long)(r0 + m - chunk_base) * lda;
    }
  }

  float acc[8][8];
  #pragma unroll
  for (int i = 0; i < 8; i++)
    #pragma unroll
    for (int j = 0; j < 8; j++) acc[i][j] = 0.f;

  for (int k0 = 0; k0 < K; k0 += BK) {
    // ---- stage A tile ----
    #pragma unroll
    for (int i = 0; i < 2; i++) {
      const int f = t + 256 * i;
      const int m = f >> 2, kq = f & 3;
      const int kk = k0 + kq * 4;
      float4 av = make_float4(0.f, 0.f, 0.f, 0.f);
      if (AMODE == 1) {
        const int tap = kk >> 10, din = kk & 1023;
        const int sin = asrow[i] + tap - 1;
        if (sin >= 0 && sin < Sq)
          av = *(const float4*)(A + ((long)(abat[i] * Sq + sin) * Dq + din));
      } else {
        if (aval[i]) av = *(const float4*)(arp[i] + kk);
      }
      As[kq * 4 + 0][m] = av.x;
      As[kq * 4 + 1][m] = av.y;
      As[kq * 4 + 2][m] = av.z;
      As[kq * 4 + 3][m] = av.w;
    }
    // ---- stage B tile ----
    if (BTRANS == 0) {
      #pragma unroll
      for (int i = 0; i < 2; i++) {
        const int f = t + 256 * i;
        const int k = f >> 5, nq = f & 31;
        const float4 bv =
            *(const float4*)(Bp + (long)(k0 + k) * ldb + n0 + nq * 4);
        *(float4*)&Bs[k][nq * 4] = bv;
      }
    } else {
      #pragma unroll
      for (int i = 0; i < 2; i++) {
        const int f = t + 256 * i;
        const int n = f >> 2, kq = f & 3;
        const float4 bv =
            *(const float4*)(Bp + (long)(n0 + n) * ldb + k0 + kq * 4);
        Bs[kq * 4 + 0][n] = bv.x;
        Bs[kq * 4 + 1][n] = bv.y;
        Bs[kq * 4 + 2][n] = bv.z;
        Bs[kq * 4 + 3][n] = bv.w;
      }
    }
    __syncthreads();
    // ---- compute ----
    #pragma unroll
    for (int k = 0; k < BK; k++) {
      float a[8], b[8];
      *(float4*)&a[0] = *(const float4*)&As[k][ty * 4];
      *(float4*)&a[4] = *(const float4*)&As[k][64 + ty * 4];
      *(float4*)&b[0] = *(const float4*)&Bs[k][tx * 4];
      *(float4*)&b[4] = *(const float4*)&Bs[k][64 + tx * 4];
      #pragma unroll
      for (int i = 0; i < 8; i++)
        #pragma unroll
        for (int j = 0; j < 8; j++) acc[i][j] = fmaf(a[i], b[j], acc[i][j]);
    }
    __syncthreads();
  }

  // ---- epilogue ----
  float bv[8];
  *(float4*)&bv[0] = *(const float4*)(biasp + n0 + tx * 4);
  *(float4*)&bv[4] = *(const float4*)(biasp + n0 + 64 + tx * 4);
  #pragma unroll
  for (int i = 0; i < 8; i++) {
    const int m_row = (i < 4) ? (ty * 4 + i) : (64 + ty * 4 + i - 4);
    float v[8];
    #pragma unroll
    for (int j = 0; j < 4; j++) {
      v[j] = acc[i][j] + bv[j];
      v[j + 4] = acc[i][j + 4] + bv[j + 4];
    }
    if (EPI == 1) {
      #pragma unroll
      for (int j = 0; j < 8; j++) v[j] = fmaxf(v[j], 0.f);
    }
    if (AMODE >= 5) {
      const int lr = lr0 + m_row;
      if (lr >= count_e) continue;
      if (EPI == 3) {
        const int r = r0 + m_row;
        const int tok = list[r];
        const float wgt = wslot[r];
        float* mrow = moe + (long)tok * Dq;
        #pragma unroll
        for (int j = 0; j < 4; j++) {
          atomicAdd(mrow + n0 + tx * 4 + j, wgt * v[j]);
          atomicAdd(mrow + n0 + 64 + tx * 4 + j, wgt * v[j + 4]);
        }
        continue;
      }
      float* crow = C + (long)(r0 + m_row - chunk_base) * ldc;
      *(float4*)(crow + n0 + tx * 4) = *(float4*)&v[0];
      *(float4*)(crow + n0 + 64 + tx * 4) = *(float4*)&v[4];
    } else {
      float* crow = C + (long)(m0 + m_row) * ldc;
      if (EPI == 2) {
        const float4 o0 = *(const float4*)(crow + n0 + tx * 4);
        const float4 o1 = *(const float4*)(crow + n0 + 64 + tx * 4);
        v[0] += o0.x; v[1] += o0.y; v[2] += o0.z; v[3] += o0.w;
        v[4] += o1.x; v[5] += o1.y; v[6] += o1.z; v[7] += o1.w;
      }
      *(float4*)(crow + n0 + tx * 4) = *(float4*)&v[0];
      *(float4*)(crow + n0 + 64 + tx * 4) = *(float4*)&v[4];
    }
  }
}

// ---------------------------------------------------------------------------
// conv_w (D,D,3) -> wt[kk][dout], kk = tap*1024 + din  (K x N row-major)
// ---------------------------------------------------------------------------
__global__ __launch_bounds__(256) void tconv_k(const float* __restrict__ cw,
                                               float* __restrict__ wt) {
  const int idx = blockIdx.x * 256 + threadIdx.x;
  const int dout = idx & 1023;
  const int kk = idx >> 10;
  const int tap = kk >> 10;
  const int din = kk & 1023;
  wt[idx] = cw[(long)dout * 3072 + din * 3 + tap];
}

// ---------------------------------------------------------------------------
// Attention on a seq chunk: "seq" axis = B(4). One wave per (n,h); lane = d.
// qc rows: l*QCN + (n - nbase), row stride 3072.
// ---------------------------------------------------------------------------
__global__ __launch_bounds__(256) void attn_k(const float* __restrict__ qc,
                                              float* __restrict__ o, int nbase) {
  const int wid = blockIdx.x * 4 + (threadIdx.x >> 6);  // [0, QCN*H)
  const int lane = threadIdx.x & 63;
  const int h = wid & 15;
  const int nl = wid >> 4;  // [0, QCN)
  float q[4], k[4], v[4];
  #pragma unroll
  for (int l = 0; l < 4; l++) {
    const long base = (long)(l * QCN + nl) * 3072 + h * 64 + lane;
    q[l] = qc[base];
    k[l] = qc[base + Dq];
    v[l] = qc[base + 2 * Dq];
  }
  float sc[4][4];
  #pragma unroll
  for (int l = 0; l < 4; l++)
    #pragma unroll
    for (int m = 0; m < 4; m++) sc[l][m] = q[l] * k[m];
  #pragma unroll
  for (int off = 32; off >= 1; off >>= 1)
    #pragma unroll
    for (int l = 0; l < 4; l++)
      #pragma unroll
      for (int m = 0; m < 4; m++) sc[l][m] += __shfl_xor(sc[l][m], off, 64);
  float p[4][4];
  #pragma unroll
  for (int l = 0; l < 4; l++) {
    float s0[4], mx = -1e30f;
    #pragma unroll
    for (int m = 0; m < 4; m++) { s0[m] = sc[l][m] * 0.125f; mx = fmaxf(mx, s0[m]); }
    float sum = 0.f;
    #pragma unroll
    for (int m = 0; m < 4; m++) { p[l][m] = __expf(s0[m] - mx); sum += p[l][m]; }
    const float inv = 1.0f / sum;
    #pragma unroll
    for (int m = 0; m < 4; m++) p[l][m] *= inv;
  }
  #pragma unroll
  for (int l = 0; l < 4; l++) {
    float ov = 0.f;
    #pragma unroll
    for (int m = 0; m < 4; m++) ov = fmaf(p[l][m], v[m], ov);
    o[(long)(l * Sq + nbase + nl) * Dq + h * 64 + lane] = ov;
  }
}

// ---------------------------------------------------------------------------
// LayerNorm (block = 256 threads, one token row of D=1024)
// ---------------------------------------------------------------------------
__device__ __forceinline__ float block_sum256(float v, float* sbuf) {
  #pragma unroll
  for (int off = 32; off >= 1; off >>= 1) v += __shfl_xor(v, off, 64);
  const int w = threadIdx.x >> 6;
  __syncthreads();
  if ((threadIdx.x & 63) == 0) sbuf[w] = v;
  __syncthreads();
  return sbuf[0] + sbuf[1] + sbuf[2] + sbuf[3];
}

__device__ __forceinline__ void ln_core(const float xv[4], const float* g,
                                        const float* bb, float* outp, long base,
                                        float* sbuf) {
  const float tot = block_sum256(xv[0] + xv[1] + xv[2] + xv[3], sbuf);
  const float mean = tot * (1.0f / 1024.0f);
  const float d0 = xv[0] - mean, d1 = xv[1] - mean, d2 = xv[2] - mean,
              d3 = xv[3] - mean;
  const float var =
      block_sum256(d0 * d0 + d1 * d1 + d2 * d2 + d3 * d3, sbuf) * (1.0f / 1024.0f);
  const float inv = 1.0f / sqrtf(var + 1e-5f);
  const int c = threadIdx.x * 4;
  const float4 gg = *(const float4*)(g + c);
  const float4 bv = *(const float4*)(bb + c);
  float4 r;
  r.x = d0 * inv * gg.x + bv.x;
  r.y = d1 * inv * gg.y + bv.y;
  r.z = d2 * inv * gg.z + bv.z;
  r.w = d3 * inv * gg.w + bv.w;
  *(float4*)(outp + base) = r;
}

__global__ __launch_bounds__(256) void ln1_k(const float* __restrict__ xc,
                                             const float* __restrict__ g,
                                             const float* __restrict__ bb,
                                             float* __restrict__ outp) {
  __shared__ float sbuf[4];
  const long base = (long)blockIdx.x * Dq + threadIdx.x * 4;
  const float4 a = *(const float4*)(xc + base);
  const float xv[4] = {a.x, a.y, a.z, a.w};
  ln_core(xv, g, bb, outp, base, sbuf);
}

__global__ __launch_bounds__(256) void ln2_k(const float* __restrict__ x1,
                                             const float* __restrict__ moe,
                                             const float* __restrict__ g,
                                             const float* __restrict__ bb,
                                             float* __restrict__ outp) {
  __shared__ float sbuf[4];
  const long base = (long)blockIdx.x * Dq + threadIdx.x * 4;
  const float4 a = *(const float4*)(x1 + base);
  const float4 m = *(const float4*)(moe + base);
  const float xv[4] = {a.x + m.x, a.y + m.y, a.z + m.z, a.w + m.w};
  ln_core(xv, g, bb, outp, base, sbuf);  // in-place safe: reads precede store
}

// ---------------------------------------------------------------------------
// MoE gating: one wave per token; top-2 of softmax, renormalized.
// ---------------------------------------------------------------------------
__global__ __launch_bounds__(256) void gate_k(const float* __restrict__ x1,
                                              const float* __restrict__ gw,
                                              const float* __restrict__ gb,
                                              int* __restrict__ e01,
                                              float* __restrict__ w01) {
  const int t = blockIdx.x * 4 + (threadIdx.x >> 6);
  const int lane = threadIdx.x & 63;
  const float* xr = x1 + (long)t * Dq;
  float acc[8];
  #pragma unroll
  for (int e = 0; e < 8; e++) acc[e] = 0.f;
  #pragma unroll
  for (int j = 0; j < 16; j++) {
    const int d = lane + 64 * j;
    const float xv = xr[d];
    const float4 g0 = *(const float4*)(gw + d * 8);
    const float4 g1 = *(const float4*)(gw + d * 8 + 4);
    acc[0] = fmaf(xv, g0.x, acc[0]);
    acc[1] = fmaf(xv, g0.y, acc[1]);
    acc[2] = fmaf(xv, g0.z, acc[2]);
    acc[3] = fmaf(xv, g0.w, acc[3]);
    acc[4] = fmaf(xv, g1.x, acc[4]);
    acc[5] = fmaf(xv, g1.y, acc[5]);
    acc[6] = fmaf(xv, g1.z, acc[6]);
    acc[7] = fmaf(xv, g1.w, acc[7]);
  }
  #pragma unroll
  for (int off = 32; off >= 1; off >>= 1)
    #pragma unroll
    for (int e = 0; e < 8; e++) acc[e] += __shfl_xor(acc[e], off, 64);
  if (lane == 0) {
    float mx = -1e30f;
    #pragma unroll
    for (int e = 0; e < 8; e++) { acc[e] += gb[e]; mx = fmaxf(mx, acc[e]); }
    float Z = 0.f, p[8];
    #pragma unroll
    for (int e = 0; e < 8; e++) { p[e] = __expf(acc[e] - mx); Z += p[e]; }
    const float invZ = 1.0f / Z;
    float b0 = -1.f, b1 = -1.f;
    int i0 = 0, i1 = 0;
    #pragma unroll
    for (int e = 0; e < 8; e++) {
      const float pe = p[e] * invZ;
      if (pe > b0) { b1 = b0; i1 = i0; b0 = pe; i0 = e; }
      else if (pe > b1) { b1 = pe; i1 = e; }
    }
    const float s = b0 + b1;
    e01[2 * t] = i0;
    e01[2 * t + 1] = i1;
    w01[2 * t] = b0 / s;
    w01[2 * t + 1] = b1 / s;
  }
}

__global__ void zero_k(int* p) {
  if (threadIdx.x < 16) p[threadIdx.x] = 0;  // counts[8] + cursor[8]
}

__global__ __launch_bounds__(256) void zerof_k(float* __restrict__ p) {
  const long i = ((long)blockIdx.x * 256 + threadIdx.x) * 4;
  *(float4*)(p + i) = make_float4(0.f, 0.f, 0.f, 0.f);
}

__global__ __launch_bounds__(256) void count_k(const int* __restrict__ e01,
                                               int* __restrict__ counts) {
  __shared__ int lc[8];
  const int tid = threadIdx.x;
  if (tid < 8) lc[tid] = 0;
  __syncthreads();
  const int t = blockIdx.x * 256 + tid;
  atomicAdd(&lc[e01[2 * t]], 1);
  atomicAdd(&lc[e01[2 * t + 1]], 1);
  __syncthreads();
  if (tid < 8) atomicAdd(&counts[tid], lc[tid]);
}

// padded prefix: each expert's region rounded up to a 128-multiple
__global__ void offs_k(const int* __restrict__ counts, int* __restrict__ offsp) {
  if (threadIdx.x == 0) {
    int a = 0;
    for (int e = 0; e < 8; e++) {
      offsp[e] = a;
      a += ((counts[e] + 127) >> 7) << 7;
    }
    offsp[8] = a;
  }
}

__global__ __launch_bounds__(256) void scatter_k(
    const int* __restrict__ e01, const float* __restrict__ w01,
    int* __restrict__ cursor, const int* __restrict__ offsp,
    int* __restrict__ list, float* __restrict__ wslot) {
  __shared__ int lc[8];
  __shared__ int gbase[8];
  const int tid = threadIdx.x;
  if (tid < 8) lc[tid] = 0;
  __syncthreads();
  const int t = blockIdx.x * 256 + tid;
  const int e0 = e01[2 * t], e1 = e01[2 * t + 1];
  const int p0 = atomicAdd(&lc[e0], 1);
  const int p1 = atomicAdd(&lc[e1], 1);
  __syncthreads();
  if (tid < 8) gbase[tid] = atomicAdd(&cursor[tid], lc[tid]);
  __syncthreads();
  const int s0 = offsp[e0] + gbase[e0] + p0;
  const int s1 = offsp[e1] + gbase[e1] + p1;
  list[s0] = t;
  list[s1] = t;
  wslot[s0] = w01[2 * t];
  wslot[s1] = w01[2 * t + 1];
}

// ---------------------------------------------------------------------------
extern "C" void kernel_launch(void* const* d_in, const int* in_sizes, int n_in,
                              void* d_out, int out_size, void* d_ws,
                              size_t ws_size, hipStream_t stream) {
  const float* x          = (const float*)d_in[0];
  const float* conv_w     = (const float*)d_in[1];
  const float* conv_b     = (const float*)d_in[2];
  const float* in_proj_w  = (const float*)d_in[3];
  const float* in_proj_b  = (const float*)d_in[4];
  const float* out_proj_w = (const float*)d_in[5];
  const float* out_proj_b = (const float*)d_in[6];
  const float* ln1_g      = (const float*)d_in[7];
  const float* ln1_b      = (const float*)d_in[8];
  const float* gate_w     = (const float*)d_in[9];
  const float* gate_b     = (const float*)d_in[10];
  const float* w1         = (const float*)d_in[11];
  const float* b1         = (const float*)d_in[12];
  const float* w2         = (const float*)d_in[13];
  const float* b2         = (const float*)d_in[14];
  const float* ln2_g      = (const float*)d_in[15];
  const float* ln2_b      = (const float*)d_in[16];

  float* ws = (float*)d_ws;
  int* si      = (int*)(ws + OFF_SM);
  int* counts  = si;
  int* cursor  = si + 8;
  int* offsp   = si + 16;
  int* e01     = si + 32;
  float* w01   = (float*)(si + 32 + 2 * Tq);
  int* list    = si + 32 + 4 * Tq;
  float* wslot = (float*)(list + PADT);
  float* xc  = ws + OFF_XC;   // conv out (phase A)
  float* moe = ws + OFF_XC;   // MoE accumulator (phase B overlay)
  float* qc  = ws + OFF_Q;    // qkv chunk
  float* wt  = ws + OFF_WT;   // transposed conv weight
  float* h   = ws + OFF_Q;    // MoE hidden chunk (phase B overlay)
  float* o   = (float*)d_out; // attention out -> x1 -> final out
  float* x1  = (float*)d_out;
  float* out = (float*)d_out;

  // 0. zero counts+cursor
  zero_k<<<1, 64, 0, stream>>>(counts);
  // 1. transpose conv weight -> (3072 x 1024) KN
  tconv_k<<<(3072 * 1024) / 256, 256, 0, stream>>>(conv_w, wt);
  // 2. conv as GEMM: xc = shift(x) @ wt + conv_b
  gemm_k<1, 0, 0><<<dim3(Dq / BN, Tq / BM), 256, 0, stream>>>(
      x, wt, conv_b, xc, 3 * Dq, Dq, Dq, Dq, nullptr, nullptr, nullptr,
      nullptr, nullptr, 0, 0, 0, 0);
  // 3. qkv + attention, chunked over seq (4 chunks of 1024)
  for (int c = 0; c < Sq / QCN; c++) {
    gemm_k<4, 1, 0><<<dim3(3 * Dq / BN, QROWS / BM), 256, 0, stream>>>(
        xc, in_proj_w, in_proj_b, qc, Dq, Dq, Dq, 3 * Dq, nullptr, nullptr,
        nullptr, nullptr, nullptr, 0, c * QCN, 0, 0);
    attn_k<<<(QCN * Hq) / 4, 256, 0, stream>>>(qc, o, c * QCN);
  }
  // 4. attn_out projection, accumulated into xc: xc += o @ W^T + b
  gemm_k<0, 1, 2><<<dim3(Dq / BN, Tq / BM), 256, 0, stream>>>(
      o, out_proj_w, out_proj_b, xc, Dq, Dq, Dq, Dq, nullptr, nullptr,
      nullptr, nullptr, nullptr, 0, 0, 0, 0);
  // 5. x1 = LN1(xc)  (x1 lives in d_out, overwriting dead o)
  ln1_k<<<Tq, 256, 0, stream>>>(xc, ln1_g, ln1_b, x1);
  // 6. zero moe accumulator (overlays dead xc region)
  zerof_k<<<Tq, 256, 0, stream>>>(moe);
  // 7. gating + compaction (padded per-expert segments)
  gate_k<<<Tq / 4, 256, 0, stream>>>(x1, gate_w, gate_b, e01, w01);
  count_k<<<Tq / 256, 256, 0, stream>>>(e01, counts);
  offs_k<<<1, 64, 0, stream>>>(counts, offsp);
  scatter_k<<<Tq / 256, 256, 0, stream>>>(e01, w01, cursor, offsp, list, wslot);
  // 8. MoE, chunked over padded slot space
  for (int c = 0; c < NC; c++) {
    const int cb = c * CH;
    gemm_k<5, 0, 1><<<dim3(HIDq / BN, CH / BM), 256, 0, stream>>>(
        x1, w1, b1, h, Dq, Dq, HIDq, HIDq, list, wslot, offsp, counts,
        nullptr, cb, 0, (long)Dq * HIDq, HIDq);
    gemm_k<6, 0, 3><<<dim3(Dq / BN, CH / BM), 256, 0, stream>>>(
        h, w2, b2, nullptr, HIDq, HIDq, Dq, Dq, list, wslot, offsp, counts,
        moe, cb, 0, (long)HIDq * Dq, Dq);
  }
  // 9. out = LN2(x1 + moe), in-place over x1
  ln2_k<<<Tq, 256, 0, stream>>>(x1, moe, ln2_g, ln2_b, out);
}

// Round 4
// 5646.456 us; speedup vs baseline: 2.2492x; 2.2492x over previous
//
#include <hip/hip_runtime.h>

typedef unsigned short u16;
typedef unsigned int u32;
typedef __attribute__((ext_vector_type(8))) short bf16x8;
typedef __attribute__((ext_vector_type(4))) float f32x4;

// ---------------------------------------------------------------------------
// Problem constants
// ---------------------------------------------------------------------------
constexpr int Bq = 4, Sq = 4096, Dq = 1024, Hq = 16, Eq = 8, HIDq = 4096;
constexpr int Tq = Bq * Sq;               // 16384 tokens
constexpr long TD = (long)Tq * Dq;        // 16,777,216
constexpr int PADT = 33792;               // padded MoE slots cap
constexpr int QCN  = 1024;                // seq chunk for qkv/attn
constexpr int QROWS = 4 * QCN;
constexpr int ECH  = 4096;                // MoE expert-chunk rows
constexpr int MAXC = 3;                   // chunks per expert (cap 12288)

// ---------------------------------------------------------------------------
// Workspace layout. Phase A (floats): [SM 262144][xc TD][qc 12.58M][wt 3.15M]
// peak 32.77M floats = 131 MB (proven safe in R2).
// Phase B overlays qc/wt span with bytes: h bf16 33.55MB | w1be 8.39 | w2be 8.39
// ---------------------------------------------------------------------------
constexpr long OFF_XC = 262144;                        // floats
constexpr long OFF_Q  = OFF_XC + TD;                   // floats
constexpr long OFF_WT = OFF_Q + (long)QROWS * 3 * Dq;  // floats
constexpr long H_B    = OFF_Q * 4;                     // bytes
constexpr long W1E_B  = H_B + (long)2 * ECH * HIDq;    // +33,554,432
constexpr long W2E_B  = W1E_B + (long)2 * Dq * HIDq;   // +8,388,608

// ---------------------------------------------------------------------------
// bf16 helpers (RNE)
// ---------------------------------------------------------------------------
__device__ __forceinline__ u32 bf1(float x) {
  u32 u = __builtin_bit_cast(u32, x);
  return (u + 0x7fffu + ((u >> 16) & 1u)) >> 16;
}
__device__ __forceinline__ u32 bfpk(float lo, float hi) {
  return bf1(lo) | (bf1(hi) << 16);
}

// ===========================================================================
// FP32 vector GEMM (proven in R2): C = op(A) @ B + bias
// AMODE: 0 direct rows | 1 conv-gather from x | 4 qkv-chunk gather
// BTRANS: 0 B KxN row-major; 1 B NxK row-major
// EPI: 0 bias store; 2 bias + C_old accumulate store
// ===========================================================================
#define BM 128
#define BN 128
#define BK 16
#define LDP 132

template <int AMODE, int BTRANS, int EPI>
__global__ __launch_bounds__(256) void gemm_f(
    const float* __restrict__ A, const float* __restrict__ Bm,
    const float* __restrict__ bias, float* __restrict__ C,
    int K, int lda, int ldb, int ldc, int nbase) {
  __shared__ float As[BK][LDP];
  __shared__ float Bs[BK][LDP];

  const int t = threadIdx.x;
  const int m0 = blockIdx.y * BM;
  const int n0 = blockIdx.x * BN;
  const int tx = t & 15, ty = t >> 4;

  const float* arp[2];
  int abat[2], asrow[2];
  #pragma unroll
  for (int i = 0; i < 2; i++) {
    const int f = t + 256 * i;
    const int m = f >> 2;
    if (AMODE == 0) {
      arp[i] = A + (long)(m0 + m) * lda;
    } else if (AMODE == 1) {
      abat[i] = (m0 + m) >> 12;
      asrow[i] = (m0 + m) & 4095;
    } else {  // AMODE == 4
      const int mm = m0 + m;
      const int l = mm >> 10;
      const int n = nbase + (mm & 1023);
      arp[i] = A + (long)(l * Sq + n) * lda;
    }
  }

  float acc[8][8];
  #pragma unroll
  for (int i = 0; i < 8; i++)
    #pragma unroll
    for (int j = 0; j < 8; j++) acc[i][j] = 0.f;

  for (int k0 = 0; k0 < K; k0 += BK) {
    #pragma unroll
    for (int i = 0; i < 2; i++) {
      const int f = t + 256 * i;
      const int m = f >> 2, kq = f & 3;
      const int kk = k0 + kq * 4;
      float4 av = make_float4(0.f, 0.f, 0.f, 0.f);
      if (AMODE == 1) {
        const int tap = kk >> 10, din = kk & 1023;
        const int sin = asrow[i] + tap - 1;
        if (sin >= 0 && sin < Sq)
          av = *(const float4*)(A + ((long)(abat[i] * Sq + sin) * Dq + din));
      } else {
        av = *(const float4*)(arp[i] + kk);
      }
      As[kq * 4 + 0][m] = av.x;
      As[kq * 4 + 1][m] = av.y;
      As[kq * 4 + 2][m] = av.z;
      As[kq * 4 + 3][m] = av.w;
    }
    if (BTRANS == 0) {
      #pragma unroll
      for (int i = 0; i < 2; i++) {
        const int f = t + 256 * i;
        const int k = f >> 5, nq = f & 31;
        const float4 bv =
            *(const float4*)(Bm + (long)(k0 + k) * ldb + n0 + nq * 4);
        *(float4*)&Bs[k][nq * 4] = bv;
      }
    } else {
      #pragma unroll
      for (int i = 0; i < 2; i++) {
        const int f = t + 256 * i;
        const int n = f >> 2, kq = f & 3;
        const float4 bv =
            *(const float4*)(Bm + (long)(n0 + n) * ldb + k0 + kq * 4);
        Bs[kq * 4 + 0][n] = bv.x;
        Bs[kq * 4 + 1][n] = bv.y;
        Bs[kq * 4 + 2][n] = bv.z;
        Bs[kq * 4 + 3][n] = bv.w;
      }
    }
    __syncthreads();
    #pragma unroll
    for (int k = 0; k < BK; k++) {
      float a[8], b[8];
      *(float4*)&a[0] = *(const float4*)&As[k][ty * 4];
      *(float4*)&a[4] = *(const float4*)&As[k][64 + ty * 4];
      *(float4*)&b[0] = *(const float4*)&Bs[k][tx * 4];
      *(float4*)&b[4] = *(const float4*)&Bs[k][64 + tx * 4];
      #pragma unroll
      for (int i = 0; i < 8; i++)
        #pragma unroll
        for (int j = 0; j < 8; j++) acc[i][j] = fmaf(a[i], b[j], acc[i][j]);
    }
    __syncthreads();
  }

  float bv[8];
  *(float4*)&bv[0] = *(const float4*)(bias + n0 + tx * 4);
  *(float4*)&bv[4] = *(const float4*)(bias + n0 + 64 + tx * 4);
  #pragma unroll
  for (int i = 0; i < 8; i++) {
    const int m_row = (i < 4) ? (ty * 4 + i) : (64 + ty * 4 + i - 4);
    float v[8];
    #pragma unroll
    for (int j = 0; j < 4; j++) {
      v[j] = acc[i][j] + bv[j];
      v[j + 4] = acc[i][j + 4] + bv[j + 4];
    }
    float* crow = C + (long)(m0 + m_row) * ldc;
    if (EPI == 2) {
      const float4 o0 = *(const float4*)(crow + n0 + tx * 4);
      const float4 o1 = *(const float4*)(crow + n0 + 64 + tx * 4);
      v[0] += o0.x; v[1] += o0.y; v[2] += o0.z; v[3] += o0.w;
      v[4] += o1.x; v[5] += o1.y; v[6] += o1.z; v[7] += o1.w;
    }
    *(float4*)(crow + n0 + tx * 4) = *(float4*)&v[0];
    *(float4*)(crow + n0 + 64 + tx * 4) = *(float4*)&v[4];
  }
}

// ===========================================================================
// BF16 MFMA GEMM (MoE only). 128x128 tile, BK=32, 4 waves x 4x4 frags of
// mfma_f32_16x16x32_bf16. B pre-converted bf16 [k/8][n][8].
// AMODE 5: A = fp32 x1 gathered via list (expert slots), cvt->bf16 staging.
// AMODE 6: A = bf16 h rows (chunk-relative).
// EPI 1: bias+relu -> bf16 h.  EPI 3: bias, weighted atomicAdd into moe.
// ===========================================================================
template <int AMODE, int EPI>
__global__ __launch_bounds__(256) void gemm_b(
    const void* __restrict__ Av, const u16* __restrict__ Bmf,
    const float* __restrict__ bias, void* __restrict__ Cv,
    int K, int lda, int ldbN, int ldc,
    const int* __restrict__ list, const float* __restrict__ wslot,
    const int* __restrict__ offsp, const int* __restrict__ counts,
    float* __restrict__ moe, int eidx, int cbase) {
  __shared__ __align__(16) u16 As[4 * 128 * 8];
  __shared__ __align__(16) u16 Bs[4 * 128 * 8];

  const int tid = threadIdx.x;
  const int rel = cbase + blockIdx.y * BM;
  const int cnt = counts[eidx];
  const int padded = ((cnt + 127) >> 7) << 7;
  if (rel >= padded) return;
  const int count_e = cnt;
  const int lr0 = rel;
  const int r0 = offsp[eidx] + rel;
  const int n0 = blockIdx.x * BN;

  const float* aptr[2];
  const u16* aptr6[2];
  bool aval[2];
  #pragma unroll
  for (int i = 0; i < 2; i++) {
    const int f = tid + 256 * i;
    const int m = f >> 2;
    aval[i] = true;
    if (AMODE == 5) {
      const int lr = lr0 + m;
      aval[i] = (lr < count_e);
      const int tok = aval[i] ? list[r0 + m] : 0;
      aptr[i] = (const float*)Av + (long)tok * lda;
    } else {
      aptr6[i] = (const u16*)Av + (long)(blockIdx.y * BM + m) * lda;
    }
  }

  f32x4 acc[4][4];
  #pragma unroll
  for (int i = 0; i < 4; i++)
    #pragma unroll
    for (int j = 0; j < 4; j++) acc[i][j] = (f32x4)(0.f);

  const int lane = tid & 63;
  const int wave = tid >> 6;
  const int wr = wave >> 1, wc = wave & 1;
  const int q = lane >> 4, l16 = lane & 15;

  for (int k0 = 0; k0 < K; k0 += 32) {
    #pragma unroll
    for (int i = 0; i < 2; i++) {
      const int f = tid + 256 * i;
      const int m = f >> 2, kc = f & 3;
      const int kk = k0 + kc * 8;
      uint4 w;
      if (AMODE == 6) {
        w = *(const uint4*)(aptr6[i] + kk);
      } else {
        float4 v0 = make_float4(0.f, 0.f, 0.f, 0.f), v1 = v0;
        if (aval[i]) {
          v0 = *(const float4*)(aptr[i] + kk);
          v1 = *(const float4*)(aptr[i] + kk + 4);
        }
        w.x = bfpk(v0.x, v0.y);
        w.y = bfpk(v0.z, v0.w);
        w.z = bfpk(v1.x, v1.y);
        w.w = bfpk(v1.z, v1.w);
      }
      *(uint4*)&As[(kc * 128 + m) * 8] = w;
    }
    const int kc0 = k0 >> 3;
    #pragma unroll
    for (int i = 0; i < 2; i++) {
      const int f = tid + 256 * i;
      const int kcb = f >> 7, n = f & 127;
      const uint4 wb =
          *(const uint4*)(Bmf + ((long)(kc0 + kcb) * ldbN + n0 + n) * 8);
      *(uint4*)&Bs[(kcb * 128 + n) * 8] = wb;
    }
    __syncthreads();
    bf16x8 af[4], bfr[4];
    #pragma unroll
    for (int mf = 0; mf < 4; mf++)
      af[mf] = *(const bf16x8*)&As[(q * 128 + wr * 64 + mf * 16 + l16) * 8];
    #pragma unroll
    for (int nf = 0; nf < 4; nf++)
      bfr[nf] = *(const bf16x8*)&Bs[(q * 128 + wc * 64 + nf * 16 + l16) * 8];
    #pragma unroll
    for (int mf = 0; mf < 4; mf++)
      #pragma unroll
      for (int nf = 0; nf < 4; nf++)
        acc[mf][nf] = __builtin_amdgcn_mfma_f32_16x16x32_bf16(
            af[mf], bfr[nf], acc[mf][nf], 0, 0, 0);
    __syncthreads();
  }

  float bcol[4];
  #pragma unroll
  for (int nf = 0; nf < 4; nf++) bcol[nf] = bias[n0 + wc * 64 + nf * 16 + l16];
  #pragma unroll
  for (int mf = 0; mf < 4; mf++) {
    #pragma unroll
    for (int reg = 0; reg < 4; reg++) {
      const int row = wr * 64 + mf * 16 + q * 4 + reg;
      if (lr0 + row >= count_e) continue;
      int tok = 0;
      float wgt = 0.f;
      if (EPI == 3) {
        tok = list[r0 + row];
        wgt = wslot[r0 + row];
      }
      #pragma unroll
      for (int nf = 0; nf < 4; nf++) {
        float v = acc[mf][nf][reg] + bcol[nf];
        const int col = n0 + wc * 64 + nf * 16 + l16;
        if (EPI == 3) {
          atomicAdd(moe + (long)tok * Dq + col, wgt * v);
        } else {
          v = fmaxf(v, 0.f);
          ((u16*)Cv)[(long)(blockIdx.y * BM + row) * ldc + col] = (u16)bf1(v);
        }
      }
    }
  }
}

// ---------------------------------------------------------------------------
// conv_w (D,D,3) -> wt[kk][dout] fp32, kk = tap*1024 + din
// ---------------------------------------------------------------------------
__global__ __launch_bounds__(256) void tconv_k(const float* __restrict__ cw,
                                               float* __restrict__ wt) {
  const int idx = blockIdx.x * 256 + threadIdx.x;
  const int dout = idx & 1023;
  const int kk = idx >> 10;
  const int tap = kk >> 10;
  const int din = kk & 1023;
  wt[idx] = cw[(long)dout * 3072 + din * 3 + tap];
}

// KxN fp32 (n contiguous) -> bf16 [kc][n][8]; grid (N/256, K/8)
__global__ __launch_bounds__(256) void kn2b_k(const float* __restrict__ src,
                                              u16* __restrict__ dst, int N) {
  const int n = blockIdx.x * 256 + threadIdx.x;
  const int kc = blockIdx.y;
  float v[8];
  #pragma unroll
  for (int j = 0; j < 8; j++) v[j] = src[(long)(kc * 8 + j) * N + n];
  uint4 w;
  w.x = bfpk(v[0], v[1]);
  w.y = bfpk(v[2], v[3]);
  w.z = bfpk(v[4], v[5]);
  w.w = bfpk(v[6], v[7]);
  *(uint4*)(dst + ((long)kc * N + n) * 8) = w;
}

// ---------------------------------------------------------------------------
// Attention on a seq chunk (fp32 qc): one wave per (n,h); lane = d.
// ---------------------------------------------------------------------------
__global__ __launch_bounds__(256) void attn_k(const float* __restrict__ qc,
                                              float* __restrict__ o, int nbase) {
  const int wid = blockIdx.x * 4 + (threadIdx.x >> 6);
  const int lane = threadIdx.x & 63;
  const int h = wid & 15;
  const int nl = wid >> 4;
  float q[4], k[4], v[4];
  #pragma unroll
  for (int l = 0; l < 4; l++) {
    const long base = (long)(l * QCN + nl) * 3072 + h * 64 + lane;
    q[l] = qc[base];
    k[l] = qc[base + Dq];
    v[l] = qc[base + 2 * Dq];
  }
  float sc[4][4];
  #pragma unroll
  for (int l = 0; l < 4; l++)
    #pragma unroll
    for (int m = 0; m < 4; m++) sc[l][m] = q[l] * k[m];
  #pragma unroll
  for (int off = 32; off >= 1; off >>= 1)
    #pragma unroll
    for (int l = 0; l < 4; l++)
      #pragma unroll
      for (int m = 0; m < 4; m++) sc[l][m] += __shfl_xor(sc[l][m], off, 64);
  float p[4][4];
  #pragma unroll
  for (int l = 0; l < 4; l++) {
    float s0[4], mx = -1e30f;
    #pragma unroll
    for (int m = 0; m < 4; m++) { s0[m] = sc[l][m] * 0.125f; mx = fmaxf(mx, s0[m]); }
    float sum = 0.f;
    #pragma unroll
    for (int m = 0; m < 4; m++) { p[l][m] = __expf(s0[m] - mx); sum += p[l][m]; }
    const float inv = 1.0f / sum;
    #pragma unroll
    for (int m = 0; m < 4; m++) p[l][m] *= inv;
  }
  #pragma unroll
  for (int l = 0; l < 4; l++) {
    float ov = 0.f;
    #pragma unroll
    for (int m = 0; m < 4; m++) ov = fmaf(p[l][m], v[m], ov);
    o[(long)(l * Sq + nbase + nl) * Dq + h * 64 + lane] = ov;
  }
}

// ---------------------------------------------------------------------------
// LayerNorm
// ---------------------------------------------------------------------------
__device__ __forceinline__ float block_sum256(float v, float* sbuf) {
  #pragma unroll
  for (int off = 32; off >= 1; off >>= 1) v += __shfl_xor(v, off, 64);
  const int w = threadIdx.x >> 6;
  __syncthreads();
  if ((threadIdx.x & 63) == 0) sbuf[w] = v;
  __syncthreads();
  return sbuf[0] + sbuf[1] + sbuf[2] + sbuf[3];
}

__device__ __forceinline__ void ln_core(const float xv[4], const float* g,
                                        const float* bb, float* outp, long base,
                                        float* sbuf) {
  const float tot = block_sum256(xv[0] + xv[1] + xv[2] + xv[3], sbuf);
  const float mean = tot * (1.0f / 1024.0f);
  const float d0 = xv[0] - mean, d1 = xv[1] - mean, d2 = xv[2] - mean,
              d3 = xv[3] - mean;
  const float var =
      block_sum256(d0 * d0 + d1 * d1 + d2 * d2 + d3 * d3, sbuf) * (1.0f / 1024.0f);
  const float inv = 1.0f / sqrtf(var + 1e-5f);
  const int c = threadIdx.x * 4;
  const float4 gg = *(const float4*)(g + c);
  const float4 bv = *(const float4*)(bb + c);
  float4 r;
  r.x = d0 * inv * gg.x + bv.x;
  r.y = d1 * inv * gg.y + bv.y;
  r.z = d2 * inv * gg.z + bv.z;
  r.w = d3 * inv * gg.w + bv.w;
  *(float4*)(outp + base) = r;
}

__global__ __launch_bounds__(256) void ln1_k(const float* __restrict__ xc,
                                             const float* __restrict__ g,
                                             const float* __restrict__ bb,
                                             float* __restrict__ outp) {
  __shared__ float sbuf[4];
  const long base = (long)blockIdx.x * Dq + threadIdx.x * 4;
  const float4 a = *(const float4*)(xc + base);
  const float xv[4] = {a.x, a.y, a.z, a.w};
  ln_core(xv, g, bb, outp, base, sbuf);
}

__global__ __launch_bounds__(256) void ln2_k(const float* __restrict__ x1,
                                             const float* __restrict__ moe,
                                             const float* __restrict__ g,
                                             const float* __restrict__ bb,
                                             float* __restrict__ outp) {
  __shared__ float sbuf[4];
  const long base = (long)blockIdx.x * Dq + threadIdx.x * 4;
  const float4 a = *(const float4*)(x1 + base);
  const float4 m = *(const float4*)(moe + base);
  const float xv[4] = {a.x + m.x, a.y + m.y, a.z + m.z, a.w + m.w};
  ln_core(xv, g, bb, outp, base, sbuf);
}

// ---------------------------------------------------------------------------
// MoE gating + compaction (fp32 x1 — proven in R2)
// ---------------------------------------------------------------------------
__global__ __launch_bounds__(256) void gate_k(const float* __restrict__ x1,
                                              const float* __restrict__ gw,
                                              const float* __restrict__ gb,
                                              int* __restrict__ e01,
                                              float* __restrict__ w01) {
  const int t = blockIdx.x * 4 + (threadIdx.x >> 6);
  const int lane = threadIdx.x & 63;
  const float* xr = x1 + (long)t * Dq;
  float acc[8];
  #pragma unroll
  for (int e = 0; e < 8; e++) acc[e] = 0.f;
  #pragma unroll
  for (int j = 0; j < 16; j++) {
    const int d = lane + 64 * j;
    const float xv = xr[d];
    const float4 g0 = *(const float4*)(gw + d * 8);
    const float4 g1 = *(const float4*)(gw + d * 8 + 4);
    acc[0] = fmaf(xv, g0.x, acc[0]);
    acc[1] = fmaf(xv, g0.y, acc[1]);
    acc[2] = fmaf(xv, g0.z, acc[2]);
    acc[3] = fmaf(xv, g0.w, acc[3]);
    acc[4] = fmaf(xv, g1.x, acc[4]);
    acc[5] = fmaf(xv, g1.y, acc[5]);
    acc[6] = fmaf(xv, g1.z, acc[6]);
    acc[7] = fmaf(xv, g1.w, acc[7]);
  }
  #pragma unroll
  for (int off = 32; off >= 1; off >>= 1)
    #pragma unroll
    for (int e = 0; e < 8; e++) acc[e] += __shfl_xor(acc[e], off, 64);
  if (lane == 0) {
    float mx = -1e30f;
    #pragma unroll
    for (int e = 0; e < 8; e++) { acc[e] += gb[e]; mx = fmaxf(mx, acc[e]); }
    float Z = 0.f, p[8];
    #pragma unroll
    for (int e = 0; e < 8; e++) { p[e] = __expf(acc[e] - mx); Z += p[e]; }
    const float invZ = 1.0f / Z;
    float b0 = -1.f, b1 = -1.f;
    int i0 = 0, i1 = 0;
    #pragma unroll
    for (int e = 0; e < 8; e++) {
      const float pe = p[e] * invZ;
      if (pe > b0) { b1 = b0; i1 = i0; b0 = pe; i0 = e; }
      else if (pe > b1) { b1 = pe; i1 = e; }
    }
    const float s = b0 + b1;
    e01[2 * t] = i0;
    e01[2 * t + 1] = i1;
    w01[2 * t] = b0 / s;
    w01[2 * t + 1] = b1 / s;
  }
}

__global__ void zero_k(int* p) {
  if (threadIdx.x < 16) p[threadIdx.x] = 0;
}

__global__ __launch_bounds__(256) void zerof_k(float* __restrict__ p) {
  const long i = ((long)blockIdx.x * 256 + threadIdx.x) * 4;
  *(float4*)(p + i) = make_float4(0.f, 0.f, 0.f, 0.f);
}

__global__ __launch_bounds__(256) void count_k(const int* __restrict__ e01,
                                               int* __restrict__ counts) {
  __shared__ int lc[8];
  const int tid = threadIdx.x;
  if (tid < 8) lc[tid] = 0;
  __syncthreads();
  const int t = blockIdx.x * 256 + tid;
  atomicAdd(&lc[e01[2 * t]], 1);
  atomicAdd(&lc[e01[2 * t + 1]], 1);
  __syncthreads();
  if (tid < 8) atomicAdd(&counts[tid], lc[tid]);
}

__global__ void offs_k(const int* __restrict__ counts, int* __restrict__ offsp) {
  if (threadIdx.x == 0) {
    int a = 0;
    for (int e = 0; e < 8; e++) {
      offsp[e] = a;
      a += ((counts[e] + 127) >> 7) << 7;
    }
    offsp[8] = a;
  }
}

__global__ __launch_bounds__(256) void scatter_k(
    const int* __restrict__ e01, const float* __restrict__ w01,
    int* __restrict__ cursor, const int* __restrict__ offsp,
    int* __restrict__ list, float* __restrict__ wslot) {
  __shared__ int lc[8];
  __shared__ int gbase[8];
  const int tid = threadIdx.x;
  if (tid < 8) lc[tid] = 0;
  __syncthreads();
  const int t = blockIdx.x * 256 + tid;
  const int e0 = e01[2 * t], e1 = e01[2 * t + 1];
  const int p0 = atomicAdd(&lc[e0], 1);
  const int p1 = atomicAdd(&lc[e1], 1);
  __syncthreads();
  if (tid < 8) gbase[tid] = atomicAdd(&cursor[tid], lc[tid]);
  __syncthreads();
  const int s0 = offsp[e0] + gbase[e0] + p0;
  const int s1 = offsp[e1] + gbase[e1] + p1;
  list[s0] = t;
  list[s1] = t;
  wslot[s0] = w01[2 * t];
  wslot[s1] = w01[2 * t + 1];
}

// ---------------------------------------------------------------------------
extern "C" void kernel_launch(void* const* d_in, const int* in_sizes, int n_in,
                              void* d_out, int out_size, void* d_ws,
                              size_t ws_size, hipStream_t stream) {
  const float* x          = (const float*)d_in[0];
  const float* conv_w     = (const float*)d_in[1];
  const float* conv_b     = (const float*)d_in[2];
  const float* in_proj_w  = (const float*)d_in[3];
  const float* in_proj_b  = (const float*)d_in[4];
  const float* out_proj_w = (const float*)d_in[5];
  const float* out_proj_b = (const float*)d_in[6];
  const float* ln1_g      = (const float*)d_in[7];
  const float* ln1_b      = (const float*)d_in[8];
  const float* gate_w     = (const float*)d_in[9];
  const float* gate_b     = (const float*)d_in[10];
  const float* w1         = (const float*)d_in[11];
  const float* b1         = (const float*)d_in[12];
  const float* w2         = (const float*)d_in[13];
  const float* b2         = (const float*)d_in[14];
  const float* ln2_g      = (const float*)d_in[15];
  const float* ln2_b      = (const float*)d_in[16];

  float* ws = (float*)d_ws;
  char* wsb = (char*)d_ws;
  int* si      = (int*)ws;
  int* counts  = si;
  int* cursor  = si + 8;
  int* offsp   = si + 16;
  int* e01     = si + 32;
  float* w01   = (float*)(si + 32 + 2 * Tq);
  int* list    = si + 32 + 4 * Tq;
  float* wslot = (float*)(list + PADT);

  float* xc   = ws + OFF_XC;      // conv out (A) / moe accumulator (B)
  float* moe  = ws + OFF_XC;
  float* qc   = ws + OFF_Q;       // qkv chunk fp32 (A)
  float* wt   = ws + OFF_WT;      // conv weight fp32 (A)
  u16* h      = (u16*)(wsb + H_B);     // MoE hidden bf16 (B)
  u16* w1be   = (u16*)(wsb + W1E_B);   // per-expert bf16 weights (B)
  u16* w2be   = (u16*)(wsb + W2E_B);
  float* o    = (float*)d_out;    // attn out -> x1 -> final out
  float* x1   = (float*)d_out;
  float* out  = (float*)d_out;

  zero_k<<<1, 64, 0, stream>>>(counts);
  tconv_k<<<(3072 * 1024) / 256, 256, 0, stream>>>(conv_w, wt);
  // conv as GEMM: xc = shift(x) @ wt + conv_b (fp32)
  gemm_f<1, 0, 0><<<dim3(Dq / BN, Tq / BM), 256, 0, stream>>>(
      x, wt, conv_b, xc, 3 * Dq, Dq, Dq, Dq, 0);
  // qkv + attention, 4 seq chunks of 1024 (fp32)
  for (int c = 0; c < Sq / QCN; c++) {
    gemm_f<4, 1, 0><<<dim3(3 * Dq / BN, QROWS / BM), 256, 0, stream>>>(
        xc, in_proj_w, in_proj_b, qc, Dq, Dq, Dq, 3 * Dq, c * QCN);
    attn_k<<<(QCN * Hq) / 4, 256, 0, stream>>>(qc, o, c * QCN);
  }
  // attn-out projection accumulated into xc (fp32)
  gemm_f<0, 1, 2><<<dim3(Dq / BN, Tq / BM), 256, 0, stream>>>(
      o, out_proj_w, out_proj_b, xc, Dq, Dq, Dq, Dq, 0);
  // x1 = LN1(xc) into d_out
  ln1_k<<<Tq, 256, 0, stream>>>(xc, ln1_g, ln1_b, x1);
  // moe accumulator = 0 (overlays dead xc)
  zerof_k<<<Tq, 256, 0, stream>>>(moe);
  // gating + compaction (fp32 x1 — selection bit-stable vs reference)
  gate_k<<<Tq / 4, 256, 0, stream>>>(x1, gate_w, gate_b, e01, w01);
  count_k<<<Tq / 256, 256, 0, stream>>>(e01, counts);
  offs_k<<<1, 64, 0, stream>>>(counts, offsp);
  scatter_k<<<Tq / 256, 256, 0, stream>>>(e01, w01, cursor, offsp, list, wslot);
  // MoE: per-expert bf16 weight streaming + MFMA GEMMs
  for (int e = 0; e < Eq; e++) {
    kn2b_k<<<dim3(HIDq / 256, Dq / 8), 256, 0, stream>>>(
        w1 + (long)e * Dq * HIDq, w1be, HIDq);
    kn2b_k<<<dim3(Dq / 256, HIDq / 8), 256, 0, stream>>>(
        w2 + (long)e * HIDq * Dq, w2be, Dq);
    for (int c = 0; c < MAXC; c++) {
      gemm_b<5, 1><<<dim3(HIDq / BN, ECH / BM), 256, 0, stream>>>(
          x1, w1be, b1 + (long)e * HIDq, h, Dq, Dq, HIDq, HIDq,
          list, wslot, offsp, counts, nullptr, e, c * ECH);
      gemm_b<6, 3><<<dim3(Dq / BN, ECH / BM), 256, 0, stream>>>(
          h, w2be, b2 + (long)e * Dq, nullptr, HIDq, HIDq, Dq, Dq,
          list, wslot, offsp, counts, moe, e, c * ECH);
    }
  }
  // out = LN2(x1 + moe)
  ln2_k<<<Tq, 256, 0, stream>>>(x1, moe, ln2_g, ln2_b, out);
}